// Round 10
// baseline (35.282 us; speedup 1.0000x reference)
//
#include <hip/hip_runtime.h>
#include <hip/hip_bf16.h>

#define DIM 256
#define NAGENT 64
#define NBATCH 256

typedef __bf16 bf16_t;
typedef bf16_t bf16x4 __attribute__((ext_vector_type(4)));
typedef bf16_t bf16x8 __attribute__((ext_vector_type(8)));
typedef float f32x4 __attribute__((ext_vector_type(4)));

// One GEMM stage: Xout[64][256] = Xin @ W^T + bias  (optionally relu+global store)
// gin/gout are XOR-swizzled bf16 LDS tiles; W,bias fp32 global (L2-hot).
// 8 waves: wave w -> cols w*32..+31, rows 0..63 (4 rt x 2 ct of 16x16x32 MFMA).
template <bool FINAL>
__device__ __forceinline__ void gemm_stage(
    const bf16_t* gin, const float* __restrict__ W,
    const float* __restrict__ bias, bf16_t* gout,
    float* __restrict__ gmem_out, int w, int lane) {
  const int lrow = lane & 15, lgrp = lane >> 4;

  f32x4 acc[4][2];
#pragma unroll
  for (int rt = 0; rt < 4; ++rt)
#pragma unroll
    for (int ct = 0; ct < 2; ++ct) acc[rt][ct] = (f32x4){0.f, 0.f, 0.f, 0.f};

  float bv[2];
#pragma unroll
  for (int ct = 0; ct < 2; ++ct) bv[ct] = bias[w * 32 + ct * 16 + lrow];

#pragma unroll
  for (int kk = 0; kk < 8; ++kk) {
    const int k0 = kk * 32 + lgrp * 8;
    bf16x8 bfrag[2];
#pragma unroll
    for (int ct = 0; ct < 2; ++ct) {
      const int col = w * 32 + ct * 16 + lrow;
      const f32x4 w0 = *(const f32x4*)&W[col * DIM + k0];
      const f32x4 w1 = *(const f32x4*)&W[col * DIM + k0 + 4];
      bf16x8 bf;
      bf[0] = (bf16_t)w0[0]; bf[1] = (bf16_t)w0[1];
      bf[2] = (bf16_t)w0[2]; bf[3] = (bf16_t)w0[3];
      bf[4] = (bf16_t)w1[0]; bf[5] = (bf16_t)w1[1];
      bf[6] = (bf16_t)w1[2]; bf[7] = (bf16_t)w1[3];
      bfrag[ct] = bf;
    }
#pragma unroll
    for (int rt = 0; rt < 4; ++rt) {
      const int arow = rt * 16 + lrow;
      const bf16x8 afrag =
          *(const bf16x8*)&gin[arow * DIM + (k0 ^ ((arow & 7) << 3))];
      acc[rt][0] = __builtin_amdgcn_mfma_f32_16x16x32_bf16(afrag, bfrag[0], acc[rt][0], 0, 0, 0);
      acc[rt][1] = __builtin_amdgcn_mfma_f32_16x16x32_bf16(afrag, bfrag[1], acc[rt][1], 0, 0, 0);
    }
  }

  // epilogue: C/D layout col=lane&15, row=(lane>>4)*4+reg  [m89-verified]
#pragma unroll
  for (int ct = 0; ct < 2; ++ct) {
    const int col = w * 32 + ct * 16 + lrow;
#pragma unroll
    for (int rt = 0; rt < 4; ++rt) {
#pragma unroll
      for (int r = 0; r < 4; ++r) {
        const int row = rt * 16 + lgrp * 4 + r;
        float val = acc[rt][ct][r] + bv[ct];
        if (FINAL) {
          gmem_out[row * DIM + col] = val > 0.f ? val : 0.f;
        } else {
          gout[row * DIM + (col ^ ((row & 7) << 3))] = (bf16_t)val;
        }
      }
    }
  }
}

// Single fused kernel. Block b (256 blocks x 512 threads):
//   phase 0: single-pass h read (f32x4), col sums, g = mix(h) -> gA (bf16 swz)
//   stage 1: gB = g @ Wa^T + ba
//   stage 2: gA = gB @ Ws^T + bs
//   stage 3: out = relu(gA @ Wh^T + bh)
__global__ __launch_bounds__(512) void mac3_kernel(
    const float* __restrict__ h,
    const float* __restrict__ Wa, const float* __restrict__ ba,
    const float* __restrict__ Ws, const float* __restrict__ bs,
    const float* __restrict__ Wh, const float* __restrict__ bh,
    float* __restrict__ out) {
  const int b = blockIdx.x;
  const int t = threadIdx.x;
  const int cg = t & 63;   // cols cg*4 .. +3
  const int rg = t >> 6;   // rows rg*8 .. +7 ; also wave id

  __shared__ __align__(16) bf16_t gA[NAGENT * DIM];  // 32 KB
  __shared__ __align__(16) bf16_t gB[NAGENT * DIM];  // 32 KB
  __shared__ f32x4 ps[8][64];                        // 8 KB

  const float* hb = h + (size_t)b * NAGENT * DIM;

  // ---- phase 0: h single pass, column sums, g build (verified R4 pattern) ----
  f32x4 v[8];
  f32x4 s4 = {0.f, 0.f, 0.f, 0.f};
#pragma unroll
  for (int i = 0; i < 8; ++i) {
    v[i] = *(const f32x4*)&hb[(rg * 8 + i) * DIM + cg * 4];
    s4 += v[i];
  }
  ps[rg][cg] = s4;
  __syncthreads();
  f32x4 hs = ps[0][cg];
#pragma unroll
  for (int r = 1; r < 8; ++r) hs += ps[r][cg];

  const float inv = 1.0f / 63.0f;
#pragma unroll
  for (int i = 0; i < 8; ++i) {
    const int row = rg * 8 + i;
    const f32x4 gv = (hs - v[i]) * inv;
    bf16x4 gb;
    gb[0] = (bf16_t)gv[0]; gb[1] = (bf16_t)gv[1];
    gb[2] = (bf16_t)gv[2]; gb[3] = (bf16_t)gv[3];
    *(bf16x4*)&gA[row * DIM + ((cg * 4) ^ ((row & 7) << 3))] = gb;
  }
  __syncthreads();

  // ---- three chained GEMM stages ----
  const int w = rg, lane = t & 63;
  float* ob = out + (size_t)b * NAGENT * DIM;

  gemm_stage<false>(gA, Wa, ba, gB, nullptr, w, lane);
  __syncthreads();
  gemm_stage<false>(gB, Ws, bs, gA, nullptr, w, lane);
  __syncthreads();
  gemm_stage<true>(gA, Wh, bh, nullptr, ob, w, lane);
}

extern "C" void kernel_launch(void* const* d_in, const int* in_sizes, int n_in,
                              void* d_out, int out_size, void* d_ws, size_t ws_size,
                              hipStream_t stream) {
  const float* h  = (const float*)d_in[0];  // hidden_state (16384,256)
  const float* Wa = (const float*)d_in[1];  // W_act (256,256)
  const float* ba = (const float*)d_in[2];  // b_act (256,)
  const float* Ws = (const float*)d_in[3];  // W_sum (256,256)
  const float* bs = (const float*)d_in[4];  // b_sum (256,)
  const float* Wh = (const float*)d_in[5];  // W_head (256,256)
  const float* bh = (const float*)d_in[6];  // b_head (256,)
  float* out = (float*)d_out;

  mac3_kernel<<<NBATCH, 512, 0, stream>>>(h, Wa, ba, Ws, bs, Wh, bh, out);
}

// Round 11
// 25.276 us; speedup vs baseline: 1.3959x; 1.3959x over previous
//
#include <hip/hip_runtime.h>
#include <hip/hip_bf16.h>

#define DIM 256
#define NAGENT 64
#define NBATCH 256

typedef __bf16 bf16_t;
typedef bf16_t bf16x4 __attribute__((ext_vector_type(4)));
typedef bf16_t bf16x8 __attribute__((ext_vector_type(8)));
typedef float f32x4 __attribute__((ext_vector_type(4)));

// Prep: 128 blocks x 1024 threads; block nb computes rows nb*2..+1 of
// Wc = bf16(Wh @ Ws @ Wa) and bc rows.
// Each Ws/Wa f32x4 load reused across 2 rows -> grid L2 traffic 64 MB (~1.9us);
// 16 independent loads per thread per stage; 16 waves/CU hide L2 latency.
__global__ __launch_bounds__(1024) void prep_kernel(
    const float* __restrict__ Wh, const float* __restrict__ Ws,
    const float* __restrict__ Wa, const float* __restrict__ ba,
    const float* __restrict__ bs, const float* __restrict__ bh,
    bf16_t* __restrict__ Wc, float* __restrict__ bcw) {
  const int i0 = blockIdx.x * 2;
  const int t = threadIdx.x;
  const int jg = t & 63;     // output cols jg*4..+3
  const int kc = t >> 6;     // k-chunk 0..15 (16 k's each)

  __shared__ float whl[2][DIM];       // 2 KB : 2 Wh rows
  __shared__ float t1l[2][DIM];       // 2 KB : 2 Whs rows
  __shared__ f32x4 part[16][2][64];   // 32 KB: partials [kc][row][jg]

  if (t < 2 * DIM) ((float*)whl)[t] = Wh[i0 * DIM + t];
  __syncthreads();

  // ---- stage 1: t1[r] = whl[r] @ Ws ----
  {
    f32x4 a0 = {0,0,0,0}, a1 = {0,0,0,0};
#pragma unroll
    for (int ki = 0; ki < 16; ++ki) {
      const int k = kc * 16 + ki;
      const f32x4 w4 = *(const f32x4*)&Ws[k * DIM + jg * 4];
      a0 += whl[0][k] * w4;
      a1 += whl[1][k] * w4;
    }
    part[kc][0][jg] = a0;
    part[kc][1][jg] = a1;
  }
  __syncthreads();
  if (t < 128) {
    const int r = t >> 6, c = t & 63;
    f32x4 s = part[0][r][c];
#pragma unroll
    for (int q = 1; q < 16; ++q) s += part[q][r][c];
    *(f32x4*)&t1l[r][c * 4] = s;
  }
  __syncthreads();

  // ---- stage 2: Wc[r] = t1[r] @ Wa ----
  {
    f32x4 a0 = {0,0,0,0}, a1 = {0,0,0,0};
#pragma unroll
    for (int ki = 0; ki < 16; ++ki) {
      const int k = kc * 16 + ki;
      const f32x4 w4 = *(const f32x4*)&Wa[k * DIM + jg * 4];
      a0 += t1l[0][k] * w4;
      a1 += t1l[1][k] * w4;
    }
    part[kc][0][jg] = a0;
    part[kc][1][jg] = a1;
  }
  __syncthreads();
  if (t < 128) {
    const int r = t >> 6, c = t & 63;  // wave 0 -> row 0, wave 1 -> row 1
    f32x4 s = part[0][r][c];
#pragma unroll
    for (int q = 1; q < 16; ++q) s += part[q][r][c];
    bf16x4 wb;
    wb[0] = (bf16_t)s[0]; wb[1] = (bf16_t)s[1];
    wb[2] = (bf16_t)s[2]; wb[3] = (bf16_t)s[3];
    *(bf16x4*)&Wc[(i0 + r) * DIM + c * 4] = wb;
    // bias: bc[i0+r] = dot(t1[r],ba) + dot(whl[r],bs) + bh  (wave-local reduce)
    const f32x4 t14 = *(const f32x4*)&t1l[r][c * 4];
    const f32x4 ba4 = *(const f32x4*)&ba[c * 4];
    const f32x4 wh4 = *(const f32x4*)&whl[r][c * 4];
    const f32x4 bs4 = *(const f32x4*)&bs[c * 4];
    const f32x4 pp = t14 * ba4 + wh4 * bs4;
    float p = pp[0] + pp[1] + pp[2] + pp[3];
#pragma unroll
    for (int s2 = 32; s2 > 0; s2 >>= 1) p += __shfl_down(p, s2, 64);
    if (c == 0) bcw[i0 + r] = p + bh[i0 + r];
  }
}

// Fused main (verbatim from R7, proven 23.52): split-column, block (b, half)
// builds full g for batch b, computes output cols half*128..+127.
__global__ __launch_bounds__(256) void fused_kernel(
    const float* __restrict__ h, const bf16_t* __restrict__ Wc,
    const float* __restrict__ bcw, float* __restrict__ out) {
  const int b = blockIdx.x;
  const int half = blockIdx.y;
  const int t = threadIdx.x;

  __shared__ __align__(16) bf16_t g[NAGENT * DIM];  // 32 KB, XOR-swizzled
  __shared__ f32x4 ps[4][64];                       // 4 KB

  const float* hb = h + (size_t)b * NAGENT * DIM;
  const int cg = t & 63;   // cols cg*4 .. +3
  const int rg = t >> 6;   // rows rg*16 .. +15

  f32x4 v[16];
  f32x4 s4 = {0.f, 0.f, 0.f, 0.f};
#pragma unroll
  for (int i = 0; i < 16; ++i) {
    v[i] = *(const f32x4*)&hb[(rg * 16 + i) * DIM + cg * 4];
    s4 += v[i];
  }
  ps[rg][cg] = s4;
  __syncthreads();
  f32x4 hs = ps[0][cg];
#pragma unroll
  for (int r = 1; r < 4; ++r) hs += ps[r][cg];

  const float inv = 1.0f / 63.0f;
#pragma unroll
  for (int i = 0; i < 16; ++i) {
    const int row = rg * 16 + i;
    const f32x4 gv = (hs - v[i]) * inv;
    bf16x4 gb;
    gb[0] = (bf16_t)gv[0]; gb[1] = (bf16_t)gv[1];
    gb[2] = (bf16_t)gv[2]; gb[3] = (bf16_t)gv[3];
    *(bf16x4*)&g[row * DIM + ((cg * 4) ^ ((row & 7) << 3))] = gb;
  }
  __syncthreads();

  const int w = rg, lane = t & 63;
  const int lrow = lane & 15, lgrp = lane >> 4;
  const int colbase = half * 128 + w * 32;

  f32x4 acc[4][2];
#pragma unroll
  for (int rt = 0; rt < 4; ++rt)
#pragma unroll
    for (int ct = 0; ct < 2; ++ct) acc[rt][ct] = (f32x4){0.f, 0.f, 0.f, 0.f};

#pragma unroll
  for (int kk = 0; kk < 8; ++kk) {
    const int k0 = kk * 32 + lgrp * 8;
    bf16x8 bfrag[2];
#pragma unroll
    for (int ct = 0; ct < 2; ++ct) {
      const int col = colbase + ct * 16 + lrow;
      bfrag[ct] = *(const bf16x8*)&Wc[col * DIM + k0];
    }
#pragma unroll
    for (int rt = 0; rt < 4; ++rt) {
      const int arow = rt * 16 + lrow;
      const bf16x8 afrag =
          *(const bf16x8*)&g[arow * DIM + (k0 ^ ((arow & 7) << 3))];
      acc[rt][0] = __builtin_amdgcn_mfma_f32_16x16x32_bf16(afrag, bfrag[0], acc[rt][0], 0, 0, 0);
      acc[rt][1] = __builtin_amdgcn_mfma_f32_16x16x32_bf16(afrag, bfrag[1], acc[rt][1], 0, 0, 0);
    }
  }

  // epilogue: C/D layout col=lane&15, row=(lane>>4)*4+reg
  float* ob = out + (size_t)b * NAGENT * DIM;
#pragma unroll
  for (int ct = 0; ct < 2; ++ct) {
    const int col = colbase + ct * 16 + lrow;
    const float bcv = bcw[col];
#pragma unroll
    for (int rt = 0; rt < 4; ++rt) {
#pragma unroll
      for (int r = 0; r < 4; ++r) {
        const int row = rt * 16 + lgrp * 4 + r;
        const float val = acc[rt][ct][r] + bcv;
        ob[row * DIM + col] = val > 0.f ? val : 0.f;
      }
    }
  }
}

extern "C" void kernel_launch(void* const* d_in, const int* in_sizes, int n_in,
                              void* d_out, int out_size, void* d_ws, size_t ws_size,
                              hipStream_t stream) {
  const float* h  = (const float*)d_in[0];  // hidden_state (16384,256)
  const float* Wa = (const float*)d_in[1];  // W_act (256,256)
  const float* ba = (const float*)d_in[2];  // b_act (256,)
  const float* Ws = (const float*)d_in[3];  // W_sum (256,256)
  const float* bs = (const float*)d_in[4];  // b_sum (256,)
  const float* Wh = (const float*)d_in[5];  // W_head (256,256)
  const float* bh = (const float*)d_in[6];  // b_head (256,)
  float* out = (float*)d_out;

  char* ws = (char*)d_ws;
  bf16_t* Wc  = (bf16_t*)ws;                 // 128 KB
  float*  bcw = (float*)(ws + 128 * 1024);   // 1 KB

  prep_kernel<<<128, 1024, 0, stream>>>(Wh, Ws, Wa, ba, bs, bh, Wc, bcw);
  fused_kernel<<<dim3(NBATCH, 2), 256, 0, stream>>>(h, Wc, bcw, out);
}

// Round 12
// 22.847 us; speedup vs baseline: 1.5442x; 1.1063x over previous
//
#include <hip/hip_runtime.h>
#include <hip/hip_bf16.h>

#define DIM 256
#define NAGENT 64
#define NBATCH 256

typedef __bf16 bf16_t;
typedef bf16_t bf16x4 __attribute__((ext_vector_type(4)));
typedef bf16_t bf16x8 __attribute__((ext_vector_type(8)));
typedef float f32x4 __attribute__((ext_vector_type(4)));

// Prep: block b -> row b of Wc = bf16(Wh @ Ws @ Wa), bc[b].
// 256 blocks x 1024 threads (best-measured placement: all CUs, 16 waves).
// NEW: Wa chunk prefetched into registers during stage 1 so the two 256 KB
// weight streams are in flight CONCURRENTLY; stage 2 is then pure VALU.
__global__ __launch_bounds__(1024) void prep_kernel(
    const float* __restrict__ Wh, const float* __restrict__ Ws,
    const float* __restrict__ Wa, const float* __restrict__ ba,
    const float* __restrict__ bs, const float* __restrict__ bh,
    bf16_t* __restrict__ Wc, float* __restrict__ bcw) {
  const int b = blockIdx.x;
  const int t = threadIdx.x;
  const int jg = t & 63;     // output cols jg*4..+3
  const int kc = t >> 6;     // k-chunk 0..15 (16 k's each)

  __shared__ float whl[DIM];      // Wh row b
  __shared__ float t1l[DIM];      // Whs row b
  __shared__ f32x4 part[16][64];  // 16 KB partials

  if (t < 64) *(f32x4*)&whl[t * 4] = *(const f32x4*)&Wh[b * DIM + t * 4];

  // prefetch this thread's Wa chunk (independent of whl/t1) — overlaps stage 1
  f32x4 wa[16];
#pragma unroll
  for (int ki = 0; ki < 16; ++ki)
    wa[ki] = *(const f32x4*)&Wa[(kc * 16 + ki) * DIM + jg * 4];

  __syncthreads();  // whl ready

  // ---- stage 1: t1 = whl @ Ws (16 independent f32x4 loads) ----
  {
    f32x4 a = {0.f, 0.f, 0.f, 0.f};
#pragma unroll
    for (int ki = 0; ki < 16; ++ki) {
      const int k = kc * 16 + ki;
      a += whl[k] * *(const f32x4*)&Ws[k * DIM + jg * 4];
    }
    part[kc][jg] = a;
  }
  __syncthreads();
  if (t < 64) {
    f32x4 s = part[0][t];
#pragma unroll
    for (int r = 1; r < 16; ++r) s += part[r][t];
    *(f32x4*)&t1l[t * 4] = s;
  }
  __syncthreads();

  // ---- stage 2: Wc row = t1 @ Wa — pure VALU on prefetched regs ----
  {
    f32x4 a = {0.f, 0.f, 0.f, 0.f};
#pragma unroll
    for (int ki = 0; ki < 16; ++ki) a += t1l[kc * 16 + ki] * wa[ki];
    part[kc][jg] = a;
  }
  __syncthreads();
  if (t < 64) {
    f32x4 s = part[0][t];
#pragma unroll
    for (int r = 1; r < 16; ++r) s += part[r][t];
    bf16x4 wb;
    wb[0] = (bf16_t)s[0]; wb[1] = (bf16_t)s[1];
    wb[2] = (bf16_t)s[2]; wb[3] = (bf16_t)s[3];
    *(bf16x4*)&Wc[b * DIM + t * 4] = wb;
    // bc[b] = dot(t1,ba) + dot(Wh[b],bs) + bh[b]  (wave-local reduce)
    const f32x4 t14 = *(const f32x4*)&t1l[t * 4];
    const f32x4 ba4 = *(const f32x4*)&ba[t * 4];
    const f32x4 wh4 = *(const f32x4*)&whl[t * 4];
    const f32x4 bs4 = *(const f32x4*)&bs[t * 4];
    const f32x4 pp = t14 * ba4 + wh4 * bs4;
    float p = pp[0] + pp[1] + pp[2] + pp[3];
#pragma unroll
    for (int s2 = 32; s2 > 0; s2 >>= 1) p += __shfl_down(p, s2, 64);
    if (t == 0) bcw[b] = p + bh[b];
  }
}

// Fused main: R4-style single block per batch (one h read), 512 threads.
// NEW: each wave's 16 B-fragments (its 32 Wc rows) prefetched into registers
// during the h phase — GEMM then runs on LDS afrag + reg bfrag only.
__global__ __launch_bounds__(512) void fused_kernel(
    const float* __restrict__ h, const bf16_t* __restrict__ Wc,
    const float* __restrict__ bcw, float* __restrict__ out) {
  const int b = blockIdx.x;
  const int t = threadIdx.x;
  const int cg = t & 63;   // cols cg*4 .. +3
  const int rg = t >> 6;   // wave id; rows rg*8 .. +7

  __shared__ __align__(16) bf16_t g[NAGENT * DIM];  // 32 KB, XOR-swizzled
  __shared__ f32x4 ps[8][64];                       // 8 KB

  const float* hb = h + (size_t)b * NAGENT * DIM;

  // issue h loads
  f32x4 v[8];
#pragma unroll
  for (int i = 0; i < 8; ++i)
    v[i] = *(const f32x4*)&hb[(rg * 8 + i) * DIM + cg * 4];

  // prefetch B-fragments: wave rg owns cols rg*32..+31 (valid: Wc ready)
  const int lane = t & 63, lrow = lane & 15, lgrp = lane >> 4;
  bf16x8 bfrag[8][2];
#pragma unroll
  for (int kk = 0; kk < 8; ++kk) {
#pragma unroll
    for (int ct = 0; ct < 2; ++ct) {
      const int col = rg * 32 + ct * 16 + lrow;
      bfrag[kk][ct] = *(const bf16x8*)&Wc[col * DIM + kk * 32 + lgrp * 8];
    }
  }
  const float bv0 = bcw[rg * 32 + lrow];
  const float bv1 = bcw[rg * 32 + 16 + lrow];

  // column sums
  f32x4 s4 = v[0];
#pragma unroll
  for (int i = 1; i < 8; ++i) s4 += v[i];
  ps[rg][cg] = s4;
  __syncthreads();
  f32x4 hs = ps[0][cg];
#pragma unroll
  for (int r = 1; r < 8; ++r) hs += ps[r][cg];

  // g build (bf16, XOR-swizzled)
  const float inv = 1.0f / 63.0f;
#pragma unroll
  for (int i = 0; i < 8; ++i) {
    const int row = rg * 8 + i;
    const f32x4 gv = (hs - v[i]) * inv;
    bf16x4 gb;
    gb[0] = (bf16_t)gv[0]; gb[1] = (bf16_t)gv[1];
    gb[2] = (bf16_t)gv[2]; gb[3] = (bf16_t)gv[3];
    *(bf16x4*)&g[row * DIM + ((cg * 4) ^ ((row & 7) << 3))] = gb;
  }
  __syncthreads();

  // GEMM: wave rg -> cols rg*32..+31, rows 0..63
  f32x4 acc[4][2];
#pragma unroll
  for (int rt = 0; rt < 4; ++rt)
#pragma unroll
    for (int ct = 0; ct < 2; ++ct) acc[rt][ct] = (f32x4){0.f, 0.f, 0.f, 0.f};

#pragma unroll
  for (int kk = 0; kk < 8; ++kk) {
    const int k0 = kk * 32 + lgrp * 8;
#pragma unroll
    for (int rt = 0; rt < 4; ++rt) {
      const int arow = rt * 16 + lrow;
      const bf16x8 afrag =
          *(const bf16x8*)&g[arow * DIM + (k0 ^ ((arow & 7) << 3))];
      acc[rt][0] = __builtin_amdgcn_mfma_f32_16x16x32_bf16(afrag, bfrag[kk][0], acc[rt][0], 0, 0, 0);
      acc[rt][1] = __builtin_amdgcn_mfma_f32_16x16x32_bf16(afrag, bfrag[kk][1], acc[rt][1], 0, 0, 0);
    }
  }

  // epilogue: C/D layout col=lane&15, row=(lane>>4)*4+reg  [m89-verified]
  float* ob = out + (size_t)b * NAGENT * DIM;
#pragma unroll
  for (int ct = 0; ct < 2; ++ct) {
    const int col = rg * 32 + ct * 16 + lrow;
    const float bcv = ct ? bv1 : bv0;
#pragma unroll
    for (int rt = 0; rt < 4; ++rt) {
#pragma unroll
      for (int r = 0; r < 4; ++r) {
        const int row = rt * 16 + lgrp * 4 + r;
        const float val = acc[rt][ct][r] + bcv;
        ob[row * DIM + col] = val > 0.f ? val : 0.f;
      }
    }
  }
}

extern "C" void kernel_launch(void* const* d_in, const int* in_sizes, int n_in,
                              void* d_out, int out_size, void* d_ws, size_t ws_size,
                              hipStream_t stream) {
  const float* h  = (const float*)d_in[0];  // hidden_state (16384,256)
  const float* Wa = (const float*)d_in[1];  // W_act (256,256)
  const float* ba = (const float*)d_in[2];  // b_act (256,)
  const float* Ws = (const float*)d_in[3];  // W_sum (256,256)
  const float* bs = (const float*)d_in[4];  // b_sum (256,)
  const float* Wh = (const float*)d_in[5];  // W_head (256,256)
  const float* bh = (const float*)d_in[6];  // b_head (256,)
  float* out = (float*)d_out;

  char* ws = (char*)d_ws;
  bf16_t* Wc  = (bf16_t*)ws;                 // 128 KB
  float*  bcw = (float*)(ws + 128 * 1024);   // 1 KB

  prep_kernel<<<NBATCH, 1024, 0, stream>>>(Wh, Ws, Wa, ba, bs, bh, Wc, bcw);
  fused_kernel<<<NBATCH, 512, 0, stream>>>(h, Wc, bcw, out);
}